// Round 1
// baseline (240.655 us; speedup 1.0000x reference)
//
#include <hip/hip_runtime.h>
#include <hip/hip_bf16.h>

#define BATCH  2
#define SEQ    2048
#define DMODEL 1024
#define NHEAD  16
#define DHEAD  64
#define NTOK   (BATCH * SEQ)

using f32x4 = __attribute__((ext_vector_type(4))) float;
using s16x4 = __attribute__((ext_vector_type(4))) short;
using s16x8 = __attribute__((ext_vector_type(8))) short;

__device__ __forceinline__ short f2bf(float f) {
  union { float f; unsigned u; } v; v.f = f;
  unsigned r = v.u + 0x7fffu + ((v.u >> 16) & 1u);   // RNE; data has no NaN
  return (short)(r >> 16);
}

// ---------------------------------------------------------------------------
// Transpose + cast all 4 weights: W[k][n] fp32 -> Wt[n][k] bf16
// grid (16,16,4), block 256
// ---------------------------------------------------------------------------
__global__ __launch_bounds__(256) void wtrans_kernel(
    const float* __restrict__ Wq, const float* __restrict__ Wk,
    const float* __restrict__ Wv, const float* __restrict__ Wo,
    short* __restrict__ Wt) {
  __shared__ short tile[64][72];
  const float* W = blockIdx.z == 0 ? Wq : blockIdx.z == 1 ? Wk
                 : blockIdx.z == 2 ? Wv : Wo;
  short* out = Wt + (size_t)blockIdx.z * DMODEL * DMODEL;
  int k0 = blockIdx.x * 64, n0 = blockIdx.y * 64;
  int t = threadIdx.x;
#pragma unroll
  for (int i = 0; i < 4; ++i) {
    int idx = t + i * 256;
    int row = idx >> 4, c4 = idx & 15;               // row = k, c4*4 = n chunk
    f32x4 v = *(const f32x4*)(W + (size_t)(k0 + row) * DMODEL + n0 + c4 * 4);
    s16x4 p;
    p[0] = f2bf(v[0]); p[1] = f2bf(v[1]); p[2] = f2bf(v[2]); p[3] = f2bf(v[3]);
    *(s16x4*)&tile[row][c4 * 4] = p;
  }
  __syncthreads();
#pragma unroll
  for (int i = 0; i < 2; ++i) {
    int idx = t + i * 256;
    int nrow = idx >> 3, c8 = idx & 7;               // nrow = n, c8*8 = k chunk
    s16x8 p;
#pragma unroll
    for (int j = 0; j < 8; ++j) p[j] = tile[c8 * 8 + j][nrow];
    *(s16x8*)(out + (size_t)(n0 + nrow) * DMODEL + k0 + c8 * 8) = p;
  }
}

// ---------------------------------------------------------------------------
// QKV projection: X[4096][1024] fp32 @ Wt^T + b -> bf16 [b*H+h][s][d]
// sel = blockIdx.z: 0=Q (scaled 1/8), 1=K, 2=V.  grid (32,8,3), block 256.
// ---------------------------------------------------------------------------
__global__ __launch_bounds__(256) void proj_qkv_kernel(
    const float* __restrict__ Xq, const float* __restrict__ Xk,
    const float* __restrict__ Xv, const short* __restrict__ Wt,
    const float* __restrict__ bq, const float* __restrict__ bk,
    const float* __restrict__ bv, short* __restrict__ QKV) {
  __shared__ short As[128][40];
  __shared__ short Bs[128][40];
  const int sel = blockIdx.z;
  const float* X    = sel == 0 ? Xq : sel == 1 ? Xk : Xv;
  const float* bias = sel == 0 ? bq : sel == 1 ? bk : bv;
  const short* Wsel = Wt + (size_t)sel * DMODEL * DMODEL;
  short* Obuf = QKV + (size_t)sel * ((size_t)BATCH * NHEAD * SEQ * DHEAD);
  const float scale = sel == 0 ? 0.125f : 1.0f;

  int m0 = blockIdx.x * 128, n0 = blockIdx.y * 128;
  int t = threadIdx.x, wid = t >> 6, lane = t & 63;
  int lr = lane & 15, lg = lane >> 4;
  int wr = wid >> 1, wc = wid & 1;
  f32x4 acc[4][4] = {};

  for (int kt = 0; kt < DMODEL / 32; ++kt) {
    int k0 = kt * 32;
    __syncthreads();
    // stage A: 128x32 fp32 -> bf16
#pragma unroll
    for (int i = 0; i < 4; ++i) {
      int idx = t + i * 256, row = idx >> 3, c4 = idx & 7;
      f32x4 v = *(const f32x4*)(X + (size_t)(m0 + row) * DMODEL + k0 + c4 * 4);
      s16x4 p;
      p[0] = f2bf(v[0]); p[1] = f2bf(v[1]); p[2] = f2bf(v[2]); p[3] = f2bf(v[3]);
      *(s16x4*)&As[row][c4 * 4] = p;
    }
    // stage B: Wt rows (n-major, k contiguous)
#pragma unroll
    for (int i = 0; i < 2; ++i) {
      int idx = t + i * 256, row = idx >> 2, c8 = idx & 3;
      *(s16x8*)&Bs[row][c8 * 8] =
          *(const s16x8*)(Wsel + (size_t)(n0 + row) * DMODEL + k0 + c8 * 8);
    }
    __syncthreads();
    s16x8 afr[4], bfr[4];
#pragma unroll
    for (int mi = 0; mi < 4; ++mi)
      afr[mi] = *(const s16x8*)&As[wr * 64 + mi * 16 + lr][lg * 8];
#pragma unroll
    for (int ni = 0; ni < 4; ++ni)
      bfr[ni] = *(const s16x8*)&Bs[wc * 64 + ni * 16 + lr][lg * 8];
#pragma unroll
    for (int mi = 0; mi < 4; ++mi)
#pragma unroll
      for (int ni = 0; ni < 4; ++ni)
        acc[mi][ni] = __builtin_amdgcn_mfma_f32_16x16x32_bf16(
            afr[mi], bfr[ni], acc[mi][ni], 0, 0, 0);
  }
  // epilogue: C/D layout col=lane&15, row=(lane>>4)*4+r  [m89-verified]
#pragma unroll
  for (int mi = 0; mi < 4; ++mi)
#pragma unroll
    for (int ni = 0; ni < 4; ++ni) {
      int n = n0 + wc * 64 + ni * 16 + lr;
      float bv_ = bias[n];
      int h = n >> 6, d = n & 63;
#pragma unroll
      for (int r = 0; r < 4; ++r) {
        int m = m0 + wr * 64 + mi * 16 + lg * 4 + r;
        int b = m >> 11, s = m & (SEQ - 1);
        float val = (acc[mi][ni][r] + bv_) * scale;
        Obuf[((size_t)(b * NHEAD + h) * SEQ + s) * DHEAD + d] = f2bf(val);
      }
    }
}

// ---------------------------------------------------------------------------
// Flash attention: block = (q-tile of 64 rows) x (b,h). 4 waves, 16 q-rows each.
// grid (32, 32), block 256.
// ---------------------------------------------------------------------------
__global__ __launch_bounds__(256) void attn_kernel(
    const short* __restrict__ Qb, const short* __restrict__ Kb,
    const short* __restrict__ Vb, const int* __restrict__ mask,
    short* __restrict__ Ctx) {
  __shared__ short Ks[64][72];        // [key][d]
  __shared__ short Vt[64][72];        // [d][key]
  __shared__ short Ps[4][16][72];     // per-wave P tile [qrow][key]
  int qt = blockIdx.x, bh = blockIdx.y;
  int b = bh >> 4, h = bh & 15;
  int q0 = qt * 64;
  int t = threadIdx.x, wid = t >> 6, lane = t & 63;
  int lr = lane & 15, lg = lane >> 4;

  // Q fragments (rows q0 + wid*16 + lr), pre-scaled by 1/8 in projection
  const short* Qrow = Qb + ((size_t)bh * SEQ + q0 + wid * 16 + lr) * DHEAD;
  s16x8 qf[2];
  qf[0] = *(const s16x8*)(Qrow + 0 + lg * 8);
  qf[1] = *(const s16x8*)(Qrow + 32 + lg * 8);

  float m_run[4], l_run[4];
  f32x4 o_acc[4] = {};
#pragma unroll
  for (int r = 0; r < 4; ++r) { m_run[r] = -1e30f; l_run[r] = 0.f; }

  const int* mbase = mask + ((size_t)b * SEQ + q0 + wid * 16 + lg * 4) * SEQ;

  for (int kt = 0; kt < SEQ / 64; ++kt) {
    int k0 = kt * 64;
    __syncthreads();   // protect LDS reuse
    // stage K tile (coalesced)
#pragma unroll
    for (int i = 0; i < 2; ++i) {
      int idx = t + i * 256, key = idx >> 3, c8 = idx & 7;
      *(s16x8*)&Ks[key][c8 * 8] =
          *(const s16x8*)(Kb + ((size_t)bh * SEQ + k0 + key) * DHEAD + c8 * 8);
    }
    // stage V transposed (lane-per-key: conflict-free LDS writes)
#pragma unroll
    for (int i = 0; i < 2; ++i) {
      int idx = t + i * 256, key = idx & 63, c8 = idx >> 6;
      s16x8 v = *(const s16x8*)(Vb + ((size_t)bh * SEQ + k0 + key) * DHEAD + c8 * 8);
#pragma unroll
      for (int j = 0; j < 8; ++j) Vt[c8 * 8 + j][key] = v[j];
    }
    __syncthreads();

    // QK^T: scores 16 q-rows x 64 keys per wave
    f32x4 sfr[4];
#pragma unroll
    for (int nf = 0; nf < 4; ++nf) {
      s16x8 kf0 = *(const s16x8*)&Ks[nf * 16 + lr][0 + lg * 8];
      s16x8 kf1 = *(const s16x8*)&Ks[nf * 16 + lr][32 + lg * 8];
      f32x4 c = {};
      c = __builtin_amdgcn_mfma_f32_16x16x32_bf16(qf[0], kf0, c, 0, 0, 0);
      c = __builtin_amdgcn_mfma_f32_16x16x32_bf16(qf[1], kf1, c, 0, 0, 0);
      sfr[nf] = c;
    }
    // mask (mask!=0 -> -1e30)
#pragma unroll
    for (int nf = 0; nf < 4; ++nf)
#pragma unroll
      for (int r = 0; r < 4; ++r) {
        int mv = mbase[(size_t)r * SEQ + k0 + nf * 16 + lr];
        if (mv != 0) sfr[nf][r] = -1e30f;
      }
    // online softmax
    float tmax[4], tsum[4];
#pragma unroll
    for (int r = 0; r < 4; ++r) {
      tmax[r] = fmaxf(fmaxf(sfr[0][r], sfr[1][r]), fmaxf(sfr[2][r], sfr[3][r]));
    }
#pragma unroll
    for (int off = 1; off < 16; off <<= 1)
#pragma unroll
      for (int r = 0; r < 4; ++r)
        tmax[r] = fmaxf(tmax[r], __shfl_xor(tmax[r], off, 64));
    float mnew[4], scl[4];
#pragma unroll
    for (int r = 0; r < 4; ++r) {
      mnew[r] = fmaxf(m_run[r], tmax[r]);
      scl[r]  = __expf(m_run[r] - mnew[r]);
      m_run[r] = mnew[r];
    }
    float p[4][4];
#pragma unroll
    for (int nf = 0; nf < 4; ++nf)
#pragma unroll
      for (int r = 0; r < 4; ++r)
        p[nf][r] = __expf(sfr[nf][r] - mnew[r]);
#pragma unroll
    for (int r = 0; r < 4; ++r)
      tsum[r] = p[0][r] + p[1][r] + p[2][r] + p[3][r];
#pragma unroll
    for (int off = 1; off < 16; off <<= 1)
#pragma unroll
      for (int r = 0; r < 4; ++r)
        tsum[r] += __shfl_xor(tsum[r], off, 64);
#pragma unroll
    for (int r = 0; r < 4; ++r)
      l_run[r] = l_run[r] * scl[r] + tsum[r];
#pragma unroll
    for (int nf = 0; nf < 4; ++nf)
#pragma unroll
      for (int r = 0; r < 4; ++r)
        o_acc[nf][r] *= scl[r];
    // P -> LDS (bf16), re-fragment for PV
#pragma unroll
    for (int nf = 0; nf < 4; ++nf)
#pragma unroll
      for (int r = 0; r < 4; ++r)
        Ps[wid][lg * 4 + r][nf * 16 + lr] = f2bf(p[nf][r]);
    __syncthreads();
    // PV
#pragma unroll
    for (int ks = 0; ks < 2; ++ks) {
      s16x8 pf = *(const s16x8*)&Ps[wid][lr][ks * 32 + lg * 8];
#pragma unroll
      for (int nf = 0; nf < 4; ++nf) {
        s16x8 vf = *(const s16x8*)&Vt[nf * 16 + lr][ks * 32 + lg * 8];
        o_acc[nf] = __builtin_amdgcn_mfma_f32_16x16x32_bf16(pf, vf, o_acc[nf], 0, 0, 0);
      }
    }
  }
  // epilogue: ctx[b][s][h*64+d] bf16
#pragma unroll
  for (int nf = 0; nf < 4; ++nf)
#pragma unroll
    for (int r = 0; r < 4; ++r) {
      int srow = q0 + wid * 16 + lg * 4 + r;
      float val = o_acc[nf][r] / l_run[r];
      Ctx[((size_t)b * SEQ + srow) * DMODEL + h * DHEAD + nf * 16 + lr] = f2bf(val);
    }
}

// ---------------------------------------------------------------------------
// Output projection: ctx bf16 @ Wo + bo -> fp32 out.  grid (32,8), block 256.
// ---------------------------------------------------------------------------
__global__ __launch_bounds__(256) void proj_out_kernel(
    const short* __restrict__ Ctx, const short* __restrict__ Wot,
    const float* __restrict__ bo, float* __restrict__ Out) {
  __shared__ short As[128][40];
  __shared__ short Bs[128][40];
  int m0 = blockIdx.x * 128, n0 = blockIdx.y * 128;
  int t = threadIdx.x, wid = t >> 6, lane = t & 63;
  int lr = lane & 15, lg = lane >> 4;
  int wr = wid >> 1, wc = wid & 1;
  f32x4 acc[4][4] = {};

  for (int kt = 0; kt < DMODEL / 32; ++kt) {
    int k0 = kt * 32;
    __syncthreads();
#pragma unroll
    for (int i = 0; i < 2; ++i) {
      int idx = t + i * 256, row = idx >> 2, c8 = idx & 3;
      *(s16x8*)&As[row][c8 * 8] =
          *(const s16x8*)(Ctx + (size_t)(m0 + row) * DMODEL + k0 + c8 * 8);
    }
#pragma unroll
    for (int i = 0; i < 2; ++i) {
      int idx = t + i * 256, row = idx >> 2, c8 = idx & 3;
      *(s16x8*)&Bs[row][c8 * 8] =
          *(const s16x8*)(Wot + (size_t)(n0 + row) * DMODEL + k0 + c8 * 8);
    }
    __syncthreads();
    s16x8 afr[4], bfr[4];
#pragma unroll
    for (int mi = 0; mi < 4; ++mi)
      afr[mi] = *(const s16x8*)&As[wr * 64 + mi * 16 + lr][lg * 8];
#pragma unroll
    for (int ni = 0; ni < 4; ++ni)
      bfr[ni] = *(const s16x8*)&Bs[wc * 64 + ni * 16 + lr][lg * 8];
#pragma unroll
    for (int mi = 0; mi < 4; ++mi)
#pragma unroll
      for (int ni = 0; ni < 4; ++ni)
        acc[mi][ni] = __builtin_amdgcn_mfma_f32_16x16x32_bf16(
            afr[mi], bfr[ni], acc[mi][ni], 0, 0, 0);
  }
#pragma unroll
  for (int mi = 0; mi < 4; ++mi)
#pragma unroll
    for (int ni = 0; ni < 4; ++ni) {
      int n = n0 + wc * 64 + ni * 16 + lr;
      float bv_ = bo[n];
#pragma unroll
      for (int r = 0; r < 4; ++r) {
        int m = m0 + wr * 64 + mi * 16 + lg * 4 + r;
        Out[(size_t)m * DMODEL + n] = acc[mi][ni][r] + bv_;
      }
    }
}

// ---------------------------------------------------------------------------
extern "C" void kernel_launch(void* const* d_in, const int* in_sizes, int n_in,
                              void* d_out, int out_size, void* d_ws, size_t ws_size,
                              hipStream_t stream) {
  const float* key_in   = (const float*)d_in[0];
  const float* value_in = (const float*)d_in[1];
  const float* query_in = (const float*)d_in[2];
  const int*   mask     = (const int*)d_in[3];
  const float* Wq = (const float*)d_in[4];
  const float* bq = (const float*)d_in[5];
  const float* Wk = (const float*)d_in[6];
  const float* bk = (const float*)d_in[7];
  const float* Wv = (const float*)d_in[8];
  const float* bv = (const float*)d_in[9];
  const float* Wo = (const float*)d_in[10];
  const float* bo = (const float*)d_in[11];
  float* out = (float*)d_out;

  short* ws = (short*)d_ws;
  const size_t WSZ   = (size_t)DMODEL * DMODEL;        // 1M elems per weight
  const size_t QKVSZ = (size_t)BATCH * NHEAD * SEQ * DHEAD;  // 4M elems
  short* Wt  = ws;                                     // [4][1024][1024]
  short* QKV = ws + 4 * WSZ;                           // 3 x [32][2048][64]
  short* Qb  = QKV;
  short* Kb  = QKV + QKVSZ;
  short* Vb  = QKV + 2 * QKVSZ;
  short* Ctx = QKV + 3 * QKVSZ;                        // [4096][1024]

  wtrans_kernel<<<dim3(16, 16, 4), 256, 0, stream>>>(Wq, Wk, Wv, Wo, Wt);
  proj_qkv_kernel<<<dim3(32, 8, 3), 256, 0, stream>>>(
      query_in, key_in, value_in, Wt, bq, bk, bv, QKV);
  attn_kernel<<<dim3(32, 32), 256, 0, stream>>>(Qb, Kb, Vb, mask, Ctx);
  proj_out_kernel<<<dim3(32, 8), 256, 0, stream>>>(Ctx, Wt + 3 * WSZ, bo, out);
}

// Round 2
// 229.026 us; speedup vs baseline: 1.0508x; 1.0508x over previous
//
#include <hip/hip_runtime.h>
#include <hip/hip_bf16.h>

#define BATCH  2
#define SEQ    2048
#define DMODEL 1024
#define NHEAD  16
#define DHEAD  64
#define NTOK   (BATCH * SEQ)

using f32x4 = __attribute__((ext_vector_type(4))) float;
using s16x4 = __attribute__((ext_vector_type(4))) short;
using s16x8 = __attribute__((ext_vector_type(8))) short;

__device__ __forceinline__ short f2bf(float f) {
  union { float f; unsigned u; } v; v.f = f;
  unsigned r = v.u + 0x7fffu + ((v.u >> 16) & 1u);   // RNE; data has no NaN
  return (short)(r >> 16);
}

// ---------------------------------------------------------------------------
// Transpose + cast all 4 weights: W[k][n] fp32 -> Wt[n][k] bf16
// ---------------------------------------------------------------------------
__global__ __launch_bounds__(256) void wtrans_kernel(
    const float* __restrict__ Wq, const float* __restrict__ Wk,
    const float* __restrict__ Wv, const float* __restrict__ Wo,
    short* __restrict__ Wt) {
  __shared__ short tile[64][72];
  const float* W = blockIdx.z == 0 ? Wq : blockIdx.z == 1 ? Wk
                 : blockIdx.z == 2 ? Wv : Wo;
  short* out = Wt + (size_t)blockIdx.z * DMODEL * DMODEL;
  int k0 = blockIdx.x * 64, n0 = blockIdx.y * 64;
  int t = threadIdx.x;
#pragma unroll
  for (int i = 0; i < 4; ++i) {
    int idx = t + i * 256;
    int row = idx >> 4, c4 = idx & 15;
    f32x4 v = *(const f32x4*)(W + (size_t)(k0 + row) * DMODEL + n0 + c4 * 4);
    s16x4 p;
    p[0] = f2bf(v[0]); p[1] = f2bf(v[1]); p[2] = f2bf(v[2]); p[3] = f2bf(v[3]);
    *(s16x4*)&tile[row][c4 * 4] = p;
  }
  __syncthreads();
#pragma unroll
  for (int i = 0; i < 2; ++i) {
    int idx = t + i * 256;
    int nrow = idx >> 3, c8 = idx & 7;
    s16x8 p;
#pragma unroll
    for (int j = 0; j < 8; ++j) p[j] = tile[c8 * 8 + j][nrow];
    *(s16x8*)(out + (size_t)(n0 + nrow) * DMODEL + k0 + c8 * 8) = p;
  }
}

// ---------------------------------------------------------------------------
// Pack mask int32 -> bit words: Mp[b*SEQ+q][kt] bit j = mask[b][q][kt*64+j]
// ---------------------------------------------------------------------------
__global__ __launch_bounds__(256) void mpack_kernel(
    const int* __restrict__ mask, unsigned long long* __restrict__ Mp) {
  const int total_words = BATCH * SEQ * (SEQ / 64);   // 131072
  int lane = threadIdx.x & 63;
  int wv = blockIdx.x * 4 + (threadIdx.x >> 6);
  int nw = gridDim.x * 4;
  for (int w = wv; w < total_words; w += nw) {
    int mv = mask[(size_t)w * 64 + lane];
    unsigned long long bits = __ballot(mv != 0);
    if (lane == 0) Mp[w] = bits;
  }
}

// ---------------------------------------------------------------------------
// QKV projection: X fp32 @ Wt^T + b -> bf16 [b*H+h][s][d]
// Q pre-scaled by (1/8)*log2(e) for the base-2 softmax.
// ---------------------------------------------------------------------------
__global__ __launch_bounds__(256) void proj_qkv_kernel(
    const float* __restrict__ Xq, const float* __restrict__ Xk,
    const float* __restrict__ Xv, const short* __restrict__ Wt,
    const float* __restrict__ bq, const float* __restrict__ bk,
    const float* __restrict__ bv, short* __restrict__ QKV) {
  __shared__ short As[128][40];
  __shared__ short Bs[128][40];
  const int sel = blockIdx.z;
  const float* X    = sel == 0 ? Xq : sel == 1 ? Xk : Xv;
  const float* bias = sel == 0 ? bq : sel == 1 ? bk : bv;
  const short* Wsel = Wt + (size_t)sel * DMODEL * DMODEL;
  short* Obuf = QKV + (size_t)sel * ((size_t)BATCH * NHEAD * SEQ * DHEAD);
  const float scale = sel == 0 ? 0.18033688011111793f : 1.0f;  // (1/8)*log2e

  int m0 = blockIdx.x * 128, n0 = blockIdx.y * 128;
  int t = threadIdx.x, wid = t >> 6, lane = t & 63;
  int lr = lane & 15, lg = lane >> 4;
  int wr = wid >> 1, wc = wid & 1;
  f32x4 acc[4][4] = {};

  for (int kt = 0; kt < DMODEL / 32; ++kt) {
    int k0 = kt * 32;
    __syncthreads();
#pragma unroll
    for (int i = 0; i < 4; ++i) {
      int idx = t + i * 256, row = idx >> 3, c4 = idx & 7;
      f32x4 v = *(const f32x4*)(X + (size_t)(m0 + row) * DMODEL + k0 + c4 * 4);
      s16x4 p;
      p[0] = f2bf(v[0]); p[1] = f2bf(v[1]); p[2] = f2bf(v[2]); p[3] = f2bf(v[3]);
      *(s16x4*)&As[row][c4 * 4] = p;
    }
#pragma unroll
    for (int i = 0; i < 2; ++i) {
      int idx = t + i * 256, row = idx >> 2, c8 = idx & 3;
      *(s16x8*)&Bs[row][c8 * 8] =
          *(const s16x8*)(Wsel + (size_t)(n0 + row) * DMODEL + k0 + c8 * 8);
    }
    __syncthreads();
    s16x8 afr[4], bfr[4];
#pragma unroll
    for (int mi = 0; mi < 4; ++mi)
      afr[mi] = *(const s16x8*)&As[wr * 64 + mi * 16 + lr][lg * 8];
#pragma unroll
    for (int ni = 0; ni < 4; ++ni)
      bfr[ni] = *(const s16x8*)&Bs[wc * 64 + ni * 16 + lr][lg * 8];
#pragma unroll
    for (int mi = 0; mi < 4; ++mi)
#pragma unroll
      for (int ni = 0; ni < 4; ++ni)
        acc[mi][ni] = __builtin_amdgcn_mfma_f32_16x16x32_bf16(
            afr[mi], bfr[ni], acc[mi][ni], 0, 0, 0);
  }
#pragma unroll
  for (int mi = 0; mi < 4; ++mi)
#pragma unroll
    for (int ni = 0; ni < 4; ++ni) {
      int n = n0 + wc * 64 + ni * 16 + lr;
      float bv_ = bias[n];
      int h = n >> 6, d = n & 63;
#pragma unroll
      for (int r = 0; r < 4; ++r) {
        int m = m0 + wr * 64 + mi * 16 + lg * 4 + r;
        int b = m >> 11, s = m & (SEQ - 1);
        float val = (acc[mi][ni][r] + bv_) * scale;
        Obuf[((size_t)(b * NHEAD + h) * SEQ + s) * DHEAD + d] = f2bf(val);
      }
    }
}

// ---------------------------------------------------------------------------
// Flash attention, swapped QK^T: lane holds full score set for q = lane&15.
// grid (32, 32), block 256. Base-2 softmax domain (Q pre-scaled by log2e/8).
// ---------------------------------------------------------------------------
__global__ __launch_bounds__(256) void attn_kernel(
    const short* __restrict__ Qb, const short* __restrict__ Kb,
    const short* __restrict__ Vb, const unsigned long long* __restrict__ Mp,
    short* __restrict__ Ctx) {
  __shared__ short Ks[64][72];        // [key][d]
  __shared__ short Vt[64][72];        // [d][key]
  __shared__ short Ps[4][16][72];     // per-wave P [q][key]
  int qt = blockIdx.x, bh = blockIdx.y;
  int b = bh >> 4, h = bh & 15;
  int q0 = qt * 64;
  int t = threadIdx.x, wid = t >> 6, lane = t & 63;
  int lr = lane & 15, lg = lane >> 4;

  // Q fragment as MFMA B-operand: col q = lr, k-rows lg*8..
  const short* Qrow = Qb + ((size_t)bh * SEQ + q0 + wid * 16 + lr) * DHEAD;
  s16x8 qf[2];
  qf[0] = *(const s16x8*)(Qrow + lg * 8);
  qf[1] = *(const s16x8*)(Qrow + 32 + lg * 8);

  float m_run = -1e30f, l_run = 0.f;   // per-lane, q = lr (replicated over lg)
  f32x4 o_acc[4] = {};

  const unsigned long long* mrow =
      Mp + ((size_t)b * SEQ + q0 + wid * 16 + lr) * (SEQ / 64);

  for (int kt = 0; kt < SEQ / 64; ++kt) {
    int k0 = kt * 64;
    unsigned long long mw = mrow[kt];  // issue before barrier
    __syncthreads();
    // stage K tile
#pragma unroll
    for (int i = 0; i < 2; ++i) {
      int idx = t + i * 256, key = idx >> 3, c8 = idx & 7;
      *(s16x8*)&Ks[key][c8 * 8] =
          *(const s16x8*)(Kb + ((size_t)bh * SEQ + k0 + key) * DHEAD + c8 * 8);
    }
    // stage V transposed
#pragma unroll
    for (int i = 0; i < 2; ++i) {
      int idx = t + i * 256, key = idx & 63, c8 = idx >> 6;
      s16x8 v = *(const s16x8*)(Vb + ((size_t)bh * SEQ + k0 + key) * DHEAD + c8 * 8);
#pragma unroll
      for (int j = 0; j < 8; ++j) Vt[c8 * 8 + j][key] = v[j];
    }
    __syncthreads();

    // S^T = K·Q^T : sfr[nf][r] = S[key = nf*16 + lg*4 + r][q = lr]
    f32x4 sfr[4];
#pragma unroll
    for (int nf = 0; nf < 4; ++nf) {
      s16x8 kf0 = *(const s16x8*)&Ks[nf * 16 + lr][lg * 8];
      s16x8 kf1 = *(const s16x8*)&Ks[nf * 16 + lr][32 + lg * 8];
      f32x4 c = {};
      c = __builtin_amdgcn_mfma_f32_16x16x32_bf16(kf0, qf[0], c, 0, 0, 0);
      c = __builtin_amdgcn_mfma_f32_16x16x32_bf16(kf1, qf[1], c, 0, 0, 0);
      sfr[nf] = c;
    }
    // mask: bit (nf*16 + lg*4 + r) of this q-row's word
    unsigned w0 = (unsigned)(mw >> (lg * 4));
    unsigned w1 = (unsigned)(mw >> (lg * 4 + 32));
#pragma unroll
    for (int nf = 0; nf < 4; ++nf)
#pragma unroll
      for (int r = 0; r < 4; ++r) {
        unsigned bit = (nf < 2) ? (w0 >> (nf * 16 + r)) : (w1 >> ((nf - 2) * 16 + r));
        if (bit & 1u) sfr[nf][r] = -1e30f;
      }
    // row max: 15 in-lane + 2 cross-lg shfls
    float tm = fmaxf(fmaxf(fmaxf(sfr[0][0], sfr[0][1]), fmaxf(sfr[0][2], sfr[0][3])),
                     fmaxf(fmaxf(sfr[1][0], sfr[1][1]), fmaxf(sfr[1][2], sfr[1][3])));
    float tm2 = fmaxf(fmaxf(fmaxf(sfr[2][0], sfr[2][1]), fmaxf(sfr[2][2], sfr[2][3])),
                      fmaxf(fmaxf(sfr[3][0], sfr[3][1]), fmaxf(sfr[3][2], sfr[3][3])));
    tm = fmaxf(tm, tm2);
    tm = fmaxf(tm, __shfl_xor(tm, 16, 64));
    tm = fmaxf(tm, __shfl_xor(tm, 32, 64));

    // defer-max: skip rescale when max growth is small (p bounded by 2^8)
    bool small = __all(tm <= m_run + 8.0f);
    if (!small) {
      float mnew = fmaxf(m_run, tm);
      float scl = __builtin_amdgcn_exp2f(m_run - mnew);
      m_run = mnew;
      l_run *= scl;
      float scl_o[4];
#pragma unroll
      for (int r = 0; r < 4; ++r) scl_o[r] = __shfl(scl, lg * 4 + r, 64);
#pragma unroll
      for (int nf = 0; nf < 4; ++nf)
#pragma unroll
        for (int r = 0; r < 4; ++r) o_acc[nf][r] *= scl_o[r];
    }
    // p = exp2(s - m), row sum
    float ps4[4];
#pragma unroll
    for (int nf = 0; nf < 4; ++nf) {
#pragma unroll
      for (int r = 0; r < 4; ++r)
        sfr[nf][r] = __builtin_amdgcn_exp2f(sfr[nf][r] - m_run);
      ps4[nf] = (sfr[nf][0] + sfr[nf][1]) + (sfr[nf][2] + sfr[nf][3]);
    }
    float ps = (ps4[0] + ps4[1]) + (ps4[2] + ps4[3]);
    ps += __shfl_xor(ps, 16, 64);
    ps += __shfl_xor(ps, 32, 64);
    l_run += ps;

    // P -> LDS (wave-private), 4 x ds_write_b64
#pragma unroll
    for (int nf = 0; nf < 4; ++nf) {
      s16x4 pk;
#pragma unroll
      for (int r = 0; r < 4; ++r) pk[r] = f2bf(sfr[nf][r]);
      *(s16x4*)&Ps[wid][lr][nf * 16 + lg * 4] = pk;
    }
    asm volatile("s_waitcnt lgkmcnt(0)" ::: "memory");
    __builtin_amdgcn_sched_barrier(0);

    // PV: O += P·V
#pragma unroll
    for (int ks = 0; ks < 2; ++ks) {
      s16x8 pf = *(const s16x8*)&Ps[wid][lr][ks * 32 + lg * 8];
#pragma unroll
      for (int nf = 0; nf < 4; ++nf) {
        s16x8 vf = *(const s16x8*)&Vt[nf * 16 + lr][ks * 32 + lg * 8];
        o_acc[nf] = __builtin_amdgcn_mfma_f32_16x16x32_bf16(pf, vf, o_acc[nf], 0, 0, 0);
      }
    }
  }
  // epilogue: o_acc[nf][r] is q = lg*4+r, d = nf*16+lr
  float l_o[4];
#pragma unroll
  for (int r = 0; r < 4; ++r) l_o[r] = __shfl(l_run, lg * 4 + r, 64);
#pragma unroll
  for (int nf = 0; nf < 4; ++nf)
#pragma unroll
    for (int r = 0; r < 4; ++r) {
      int srow = q0 + wid * 16 + lg * 4 + r;
      float val = o_acc[nf][r] / l_o[r];
      Ctx[((size_t)b * SEQ + srow) * DMODEL + h * DHEAD + nf * 16 + lr] = f2bf(val);
    }
}

// ---------------------------------------------------------------------------
// Output projection: ctx bf16 @ Wo + bo -> fp32 out
// ---------------------------------------------------------------------------
__global__ __launch_bounds__(256) void proj_out_kernel(
    const short* __restrict__ Ctx, const short* __restrict__ Wot,
    const float* __restrict__ bo, float* __restrict__ Out) {
  __shared__ short As[128][40];
  __shared__ short Bs[128][40];
  int m0 = blockIdx.x * 128, n0 = blockIdx.y * 128;
  int t = threadIdx.x, wid = t >> 6, lane = t & 63;
  int lr = lane & 15, lg = lane >> 4;
  int wr = wid >> 1, wc = wid & 1;
  f32x4 acc[4][4] = {};

  for (int kt = 0; kt < DMODEL / 32; ++kt) {
    int k0 = kt * 32;
    __syncthreads();
#pragma unroll
    for (int i = 0; i < 2; ++i) {
      int idx = t + i * 256, row = idx >> 2, c8 = idx & 3;
      *(s16x8*)&As[row][c8 * 8] =
          *(const s16x8*)(Ctx + (size_t)(m0 + row) * DMODEL + k0 + c8 * 8);
    }
#pragma unroll
    for (int i = 0; i < 2; ++i) {
      int idx = t + i * 256, row = idx >> 2, c8 = idx & 3;
      *(s16x8*)&Bs[row][c8 * 8] =
          *(const s16x8*)(Wot + (size_t)(n0 + row) * DMODEL + k0 + c8 * 8);
    }
    __syncthreads();
    s16x8 afr[4], bfr[4];
#pragma unroll
    for (int mi = 0; mi < 4; ++mi)
      afr[mi] = *(const s16x8*)&As[wr * 64 + mi * 16 + lr][lg * 8];
#pragma unroll
    for (int ni = 0; ni < 4; ++ni)
      bfr[ni] = *(const s16x8*)&Bs[wc * 64 + ni * 16 + lr][lg * 8];
#pragma unroll
    for (int mi = 0; mi < 4; ++mi)
#pragma unroll
      for (int ni = 0; ni < 4; ++ni)
        acc[mi][ni] = __builtin_amdgcn_mfma_f32_16x16x32_bf16(
            afr[mi], bfr[ni], acc[mi][ni], 0, 0, 0);
  }
#pragma unroll
  for (int mi = 0; mi < 4; ++mi)
#pragma unroll
    for (int ni = 0; ni < 4; ++ni) {
      int n = n0 + wc * 64 + ni * 16 + lr;
      float bv_ = bo[n];
#pragma unroll
      for (int r = 0; r < 4; ++r) {
        int m = m0 + wr * 64 + mi * 16 + lg * 4 + r;
        Out[(size_t)m * DMODEL + n] = acc[mi][ni][r] + bv_;
      }
    }
}

// ---------------------------------------------------------------------------
extern "C" void kernel_launch(void* const* d_in, const int* in_sizes, int n_in,
                              void* d_out, int out_size, void* d_ws, size_t ws_size,
                              hipStream_t stream) {
  const float* key_in   = (const float*)d_in[0];
  const float* value_in = (const float*)d_in[1];
  const float* query_in = (const float*)d_in[2];
  const int*   mask     = (const int*)d_in[3];
  const float* Wq = (const float*)d_in[4];
  const float* bq = (const float*)d_in[5];
  const float* Wk = (const float*)d_in[6];
  const float* bk = (const float*)d_in[7];
  const float* Wv = (const float*)d_in[8];
  const float* bv = (const float*)d_in[9];
  const float* Wo = (const float*)d_in[10];
  const float* bo = (const float*)d_in[11];
  float* out = (float*)d_out;

  short* ws = (short*)d_ws;
  const size_t WSZ   = (size_t)DMODEL * DMODEL;
  const size_t QKVSZ = (size_t)BATCH * NHEAD * SEQ * DHEAD;
  short* Wt  = ws;                         // [4][1024][1024] bf16
  short* QKV = ws + 4 * WSZ;
  short* Qb  = QKV;
  short* Kb  = QKV + QKVSZ;
  short* Vb  = QKV + 2 * QKVSZ;
  short* Ctx = QKV + 3 * QKVSZ;
  // Mp overlays the Wq-transposed region (1 MB < 2 MB), written AFTER
  // proj_qkv has consumed Wt[0] (stream-serialized).
  unsigned long long* Mp = (unsigned long long*)ws;

  wtrans_kernel<<<dim3(16, 16, 4), 256, 0, stream>>>(Wq, Wk, Wv, Wo, Wt);
  proj_qkv_kernel<<<dim3(32, 8, 3), 256, 0, stream>>>(
      query_in, key_in, value_in, Wt, bq, bk, bv, QKV);
  mpack_kernel<<<dim3(256), 256, 0, stream>>>(mask, Mp);
  attn_kernel<<<dim3(32, 32), 256, 0, stream>>>(Qb, Kb, Vb, Mp, Ctx);
  proj_out_kernel<<<dim3(32, 8), 256, 0, stream>>>(Ctx, Wt + 3 * WSZ, bo, out);
}

// Round 3
// 194.894 us; speedup vs baseline: 1.2348x; 1.1751x over previous
//
#include <hip/hip_runtime.h>
#include <hip/hip_bf16.h>

#define BATCH  2
#define SEQ    2048
#define DMODEL 1024
#define NHEAD  16
#define DHEAD  64
#define NTOK   (BATCH * SEQ)

using f32x4 = __attribute__((ext_vector_type(4))) float;
using s16x4 = __attribute__((ext_vector_type(4))) short;
using s16x8 = __attribute__((ext_vector_type(8))) short;

__device__ __forceinline__ short f2bf(float f) {
  __hip_bfloat16 h = __float2bfloat16(f);   // RNE; backend emits cvt_pk pairs
  return *(short*)&h;
}

__device__ __forceinline__ void gload_lds16(const short* g, short* l) {
  __builtin_amdgcn_global_load_lds(
      (const __attribute__((address_space(1))) void*)g,
      (__attribute__((address_space(3))) void*)l, 16, 0, 0);
}

// ---------------------------------------------------------------------------
// Transpose + cast all 4 weights: W[k][n] fp32 -> Wt[n][k] bf16
// ---------------------------------------------------------------------------
__global__ __launch_bounds__(256) void wtrans_kernel(
    const float* __restrict__ Wq, const float* __restrict__ Wk,
    const float* __restrict__ Wv, const float* __restrict__ Wo,
    short* __restrict__ Wt) {
  __shared__ short tile[64][72];
  const float* W = blockIdx.z == 0 ? Wq : blockIdx.z == 1 ? Wk
                 : blockIdx.z == 2 ? Wv : Wo;
  short* out = Wt + (size_t)blockIdx.z * DMODEL * DMODEL;
  int k0 = blockIdx.x * 64, n0 = blockIdx.y * 64;
  int t = threadIdx.x;
#pragma unroll
  for (int i = 0; i < 4; ++i) {
    int idx = t + i * 256;
    int row = idx >> 4, c4 = idx & 15;
    f32x4 v = *(const f32x4*)(W + (size_t)(k0 + row) * DMODEL + n0 + c4 * 4);
    s16x4 p;
    p[0] = f2bf(v[0]); p[1] = f2bf(v[1]); p[2] = f2bf(v[2]); p[3] = f2bf(v[3]);
    *(s16x4*)&tile[row][c4 * 4] = p;
  }
  __syncthreads();
#pragma unroll
  for (int i = 0; i < 2; ++i) {
    int idx = t + i * 256;
    int nrow = idx >> 3, c8 = idx & 7;
    s16x8 p;
#pragma unroll
    for (int j = 0; j < 8; ++j) p[j] = tile[c8 * 8 + j][nrow];
    *(s16x8*)(out + (size_t)(n0 + nrow) * DMODEL + k0 + c8 * 8) = p;
  }
}

// ---------------------------------------------------------------------------
// Pack mask int32 -> bit words: Mp[b*SEQ+q][kt] bit j = mask[b][q][kt*64+j]
// ---------------------------------------------------------------------------
__global__ __launch_bounds__(256) void mpack_kernel(
    const int* __restrict__ mask, unsigned long long* __restrict__ Mp) {
  const int total_words = BATCH * SEQ * (SEQ / 64);   // 131072
  int lane = threadIdx.x & 63;
  int wv = blockIdx.x * 4 + (threadIdx.x >> 6);
  int nw = gridDim.x * 4;
  for (int w = wv; w < total_words; w += nw) {
    int mv = mask[(size_t)w * 64 + lane];
    unsigned long long bits = __ballot(mv != 0);
    if (lane == 0) Mp[w] = bits;
  }
}

// ---------------------------------------------------------------------------
// QKV projection: X fp32 @ Wt^T + b -> bf16 [b*H+h][s][d]
// A: fp32 load + cvt staging. B: global_load_lds(16B) direct to LDS.
// Q pre-scaled by (1/8)*log2(e).  grid (32,8,3), block 256.
// ---------------------------------------------------------------------------
__global__ __launch_bounds__(256) void proj_qkv_kernel(
    const float* __restrict__ Xq, const float* __restrict__ Xk,
    const float* __restrict__ Xv, const short* __restrict__ Wt,
    const float* __restrict__ bq, const float* __restrict__ bk,
    const float* __restrict__ bv, short* __restrict__ QKV) {
  __shared__ short As[128][32];   // linear, 8KB
  __shared__ short Bs[128][32];   // linear, 8KB (glLDS dest: no padding)
  const int sel = blockIdx.z;
  const float* X    = sel == 0 ? Xq : sel == 1 ? Xk : Xv;
  const float* bias = sel == 0 ? bq : sel == 1 ? bk : bv;
  const short* Wsel = Wt + (size_t)sel * DMODEL * DMODEL;
  short* Obuf = QKV + (size_t)sel * ((size_t)BATCH * NHEAD * SEQ * DHEAD);
  const float scale = sel == 0 ? 0.18033688011111793f : 1.0f;  // (1/8)*log2e

  int m0 = blockIdx.x * 128, n0 = blockIdx.y * 128;
  int t = threadIdx.x, wid = t >> 6, lane = t & 63;
  int lr = lane & 15, lg = lane >> 4;
  int wr = wid >> 1, wc = wid & 1;
  f32x4 acc[4][4] = {};

  for (int kt = 0; kt < DMODEL / 32; ++kt) {
    int k0 = kt * 32;
    __syncthreads();
    // B: 128x32 bf16 = 8KB via global_load_lds, 2 chunks/thread
#pragma unroll
    for (int i = 0; i < 2; ++i) {
      int c = i * 256 + t;
      short* lbase = &Bs[0][0] + (size_t)((i * 256 + (t & ~63)) << 3);
      gload_lds16(Wsel + (size_t)(n0 + (c >> 2)) * DMODEL + k0 + ((c & 3) << 3),
                  lbase);
    }
    // A: 128x32 fp32 -> bf16 (2x f32x4 loads + 1 ds_write_b128 per iter)
#pragma unroll
    for (int i = 0; i < 2; ++i) {
      int idx = t + i * 256, row = idx >> 2, c8 = idx & 3;
      const float* src = X + (size_t)(m0 + row) * DMODEL + k0 + c8 * 8;
      f32x4 v0 = *(const f32x4*)src;
      f32x4 v1 = *(const f32x4*)(src + 4);
      s16x8 p;
      p[0] = f2bf(v0[0]); p[1] = f2bf(v0[1]); p[2] = f2bf(v0[2]); p[3] = f2bf(v0[3]);
      p[4] = f2bf(v1[0]); p[5] = f2bf(v1[1]); p[6] = f2bf(v1[2]); p[7] = f2bf(v1[3]);
      *(s16x8*)&As[row][c8 * 8] = p;
    }
    __syncthreads();
    s16x8 afr[4], bfr[4];
#pragma unroll
    for (int mi = 0; mi < 4; ++mi)
      afr[mi] = *(const s16x8*)&As[wr * 64 + mi * 16 + lr][lg * 8];
#pragma unroll
    for (int ni = 0; ni < 4; ++ni)
      bfr[ni] = *(const s16x8*)&Bs[wc * 64 + ni * 16 + lr][lg * 8];
#pragma unroll
    for (int mi = 0; mi < 4; ++mi)
#pragma unroll
      for (int ni = 0; ni < 4; ++ni)
        acc[mi][ni] = __builtin_amdgcn_mfma_f32_16x16x32_bf16(
            afr[mi], bfr[ni], acc[mi][ni], 0, 0, 0);
  }
#pragma unroll
  for (int mi = 0; mi < 4; ++mi)
#pragma unroll
    for (int ni = 0; ni < 4; ++ni) {
      int n = n0 + wc * 64 + ni * 16 + lr;
      float bv_ = bias[n];
      int h = n >> 6, d = n & 63;
#pragma unroll
      for (int r = 0; r < 4; ++r) {
        int m = m0 + wr * 64 + mi * 16 + lg * 4 + r;
        int b = m >> 11, s = m & (SEQ - 1);
        float val = (acc[mi][ni][r] + bv_) * scale;
        Obuf[((size_t)(b * NHEAD + h) * SEQ + s) * DHEAD + d] = f2bf(val);
      }
    }
}

// ---------------------------------------------------------------------------
// Flash attention, swapped QK^T: lane holds full score set for q = lane&15.
// grid (32, 32), block 256. Base-2 softmax domain.
// ---------------------------------------------------------------------------
__global__ __launch_bounds__(256) void attn_kernel(
    const short* __restrict__ Qb, const short* __restrict__ Kb,
    const short* __restrict__ Vb, const unsigned long long* __restrict__ Mp,
    short* __restrict__ Ctx) {
  __shared__ short Ks[64][72];        // [key][d]
  __shared__ short Vt[64][72];        // [d][key]
  __shared__ short Ps[4][16][72];     // per-wave P [q][key]
  int qt = blockIdx.x, bh = blockIdx.y;
  int b = bh >> 4, h = bh & 15;
  int q0 = qt * 64;
  int t = threadIdx.x, wid = t >> 6, lane = t & 63;
  int lr = lane & 15, lg = lane >> 4;

  const short* Qrow = Qb + ((size_t)bh * SEQ + q0 + wid * 16 + lr) * DHEAD;
  s16x8 qf[2];
  qf[0] = *(const s16x8*)(Qrow + lg * 8);
  qf[1] = *(const s16x8*)(Qrow + 32 + lg * 8);

  float m_run = -1e30f, l_run = 0.f;   // per-lane, q = lr
  f32x4 o_acc[4] = {};

  const unsigned long long* mrow =
      Mp + ((size_t)b * SEQ + q0 + wid * 16 + lr) * (SEQ / 64);

  for (int kt = 0; kt < SEQ / 64; ++kt) {
    int k0 = kt * 64;
    unsigned long long mw = mrow[kt];
    __syncthreads();
#pragma unroll
    for (int i = 0; i < 2; ++i) {
      int idx = t + i * 256, key = idx >> 3, c8 = idx & 7;
      *(s16x8*)&Ks[key][c8 * 8] =
          *(const s16x8*)(Kb + ((size_t)bh * SEQ + k0 + key) * DHEAD + c8 * 8);
    }
#pragma unroll
    for (int i = 0; i < 2; ++i) {
      int idx = t + i * 256, key = idx & 63, c8 = idx >> 6;
      s16x8 v = *(const s16x8*)(Vb + ((size_t)bh * SEQ + k0 + key) * DHEAD + c8 * 8);
#pragma unroll
      for (int j = 0; j < 8; ++j) Vt[c8 * 8 + j][key] = v[j];
    }
    __syncthreads();

    f32x4 sfr[4];
#pragma unroll
    for (int nf = 0; nf < 4; ++nf) {
      s16x8 kf0 = *(const s16x8*)&Ks[nf * 16 + lr][lg * 8];
      s16x8 kf1 = *(const s16x8*)&Ks[nf * 16 + lr][32 + lg * 8];
      f32x4 c = {};
      c = __builtin_amdgcn_mfma_f32_16x16x32_bf16(kf0, qf[0], c, 0, 0, 0);
      c = __builtin_amdgcn_mfma_f32_16x16x32_bf16(kf1, qf[1], c, 0, 0, 0);
      sfr[nf] = c;
    }
    unsigned w0 = (unsigned)(mw >> (lg * 4));
    unsigned w1 = (unsigned)(mw >> (lg * 4 + 32));
#pragma unroll
    for (int nf = 0; nf < 4; ++nf)
#pragma unroll
      for (int r = 0; r < 4; ++r) {
        unsigned bit = (nf < 2) ? (w0 >> (nf * 16 + r)) : (w1 >> ((nf - 2) * 16 + r));
        if (bit & 1u) sfr[nf][r] = -1e30f;
      }
    float tm = fmaxf(fmaxf(fmaxf(sfr[0][0], sfr[0][1]), fmaxf(sfr[0][2], sfr[0][3])),
                     fmaxf(fmaxf(sfr[1][0], sfr[1][1]), fmaxf(sfr[1][2], sfr[1][3])));
    float tm2 = fmaxf(fmaxf(fmaxf(sfr[2][0], sfr[2][1]), fmaxf(sfr[2][2], sfr[2][3])),
                      fmaxf(fmaxf(sfr[3][0], sfr[3][1]), fmaxf(sfr[3][2], sfr[3][3])));
    tm = fmaxf(tm, tm2);
    tm = fmaxf(tm, __shfl_xor(tm, 16, 64));
    tm = fmaxf(tm, __shfl_xor(tm, 32, 64));

    bool small = __all(tm <= m_run + 8.0f);
    if (!small) {
      float mnew = fmaxf(m_run, tm);
      float scl = __builtin_amdgcn_exp2f(m_run - mnew);
      m_run = mnew;
      l_run *= scl;
      float scl_o[4];
#pragma unroll
      for (int r = 0; r < 4; ++r) scl_o[r] = __shfl(scl, lg * 4 + r, 64);
#pragma unroll
      for (int nf = 0; nf < 4; ++nf)
#pragma unroll
        for (int r = 0; r < 4; ++r) o_acc[nf][r] *= scl_o[r];
    }
    float ps4[4];
#pragma unroll
    for (int nf = 0; nf < 4; ++nf) {
#pragma unroll
      for (int r = 0; r < 4; ++r)
        sfr[nf][r] = __builtin_amdgcn_exp2f(sfr[nf][r] - m_run);
      ps4[nf] = (sfr[nf][0] + sfr[nf][1]) + (sfr[nf][2] + sfr[nf][3]);
    }
    float ps = (ps4[0] + ps4[1]) + (ps4[2] + ps4[3]);
    ps += __shfl_xor(ps, 16, 64);
    ps += __shfl_xor(ps, 32, 64);
    l_run += ps;

#pragma unroll
    for (int nf = 0; nf < 4; ++nf) {
      s16x4 pk;
#pragma unroll
      for (int r = 0; r < 4; ++r) pk[r] = f2bf(sfr[nf][r]);
      *(s16x4*)&Ps[wid][lr][nf * 16 + lg * 4] = pk;
    }
    asm volatile("s_waitcnt lgkmcnt(0)" ::: "memory");
    __builtin_amdgcn_sched_barrier(0);

#pragma unroll
    for (int ks = 0; ks < 2; ++ks) {
      s16x8 pf = *(const s16x8*)&Ps[wid][lr][ks * 32 + lg * 8];
#pragma unroll
      for (int nf = 0; nf < 4; ++nf) {
        s16x8 vf = *(const s16x8*)&Vt[nf * 16 + lr][ks * 32 + lg * 8];
        o_acc[nf] = __builtin_amdgcn_mfma_f32_16x16x32_bf16(pf, vf, o_acc[nf], 0, 0, 0);
      }
    }
  }
  float l_o[4];
#pragma unroll
  for (int r = 0; r < 4; ++r) l_o[r] = __shfl(l_run, lg * 4 + r, 64);
#pragma unroll
  for (int nf = 0; nf < 4; ++nf)
#pragma unroll
    for (int r = 0; r < 4; ++r) {
      int srow = q0 + wid * 16 + lg * 4 + r;
      float val = o_acc[nf][r] / l_o[r];
      Ctx[((size_t)b * SEQ + srow) * DMODEL + h * DHEAD + nf * 16 + lr] = f2bf(val);
    }
}

// ---------------------------------------------------------------------------
// Output projection: ctx bf16 @ Wo + bo -> fp32 out.  Full m97 structure:
// both operands staged via global_load_lds.  grid (32,8), block 256.
// ---------------------------------------------------------------------------
__global__ __launch_bounds__(256) void proj_out_kernel(
    const short* __restrict__ Ctx, const short* __restrict__ Wot,
    const float* __restrict__ bo, float* __restrict__ Out) {
  __shared__ short As[128][32];
  __shared__ short Bs[128][32];
  int m0 = blockIdx.x * 128, n0 = blockIdx.y * 128;
  int t = threadIdx.x, wid = t >> 6, lane = t & 63;
  int lr = lane & 15, lg = lane >> 4;
  int wr = wid >> 1, wc = wid & 1;
  f32x4 acc[4][4] = {};

  for (int kt = 0; kt < DMODEL / 32; ++kt) {
    int k0 = kt * 32;
    __syncthreads();
#pragma unroll
    for (int i = 0; i < 2; ++i) {
      int c = i * 256 + t;
      size_t lofs = (size_t)((i * 256 + (t & ~63)) << 3);
      gload_lds16(Ctx + (size_t)(m0 + (c >> 2)) * DMODEL + k0 + ((c & 3) << 3),
                  &As[0][0] + lofs);
      gload_lds16(Wot + (size_t)(n0 + (c >> 2)) * DMODEL + k0 + ((c & 3) << 3),
                  &Bs[0][0] + lofs);
    }
    __syncthreads();
    s16x8 afr[4], bfr[4];
#pragma unroll
    for (int mi = 0; mi < 4; ++mi)
      afr[mi] = *(const s16x8*)&As[wr * 64 + mi * 16 + lr][lg * 8];
#pragma unroll
    for (int ni = 0; ni < 4; ++ni)
      bfr[ni] = *(const s16x8*)&Bs[wc * 64 + ni * 16 + lr][lg * 8];
#pragma unroll
    for (int mi = 0; mi < 4; ++mi)
#pragma unroll
      for (int ni = 0; ni < 4; ++ni)
        acc[mi][ni] = __builtin_amdgcn_mfma_f32_16x16x32_bf16(
            afr[mi], bfr[ni], acc[mi][ni], 0, 0, 0);
  }
#pragma unroll
  for (int mi = 0; mi < 4; ++mi)
#pragma unroll
    for (int ni = 0; ni < 4; ++ni) {
      int n = n0 + wc * 64 + ni * 16 + lr;
      float bv_ = bo[n];
#pragma unroll
      for (int r = 0; r < 4; ++r) {
        int m = m0 + wr * 64 + mi * 16 + lg * 4 + r;
        Out[(size_t)m * DMODEL + n] = acc[mi][ni][r] + bv_;
      }
    }
}

// ---------------------------------------------------------------------------
extern "C" void kernel_launch(void* const* d_in, const int* in_sizes, int n_in,
                              void* d_out, int out_size, void* d_ws, size_t ws_size,
                              hipStream_t stream) {
  const float* key_in   = (const float*)d_in[0];
  const float* value_in = (const float*)d_in[1];
  const float* query_in = (const float*)d_in[2];
  const int*   mask     = (const int*)d_in[3];
  const float* Wq = (const float*)d_in[4];
  const float* bq = (const float*)d_in[5];
  const float* Wk = (const float*)d_in[6];
  const float* bk = (const float*)d_in[7];
  const float* Wv = (const float*)d_in[8];
  const float* bv = (const float*)d_in[9];
  const float* Wo = (const float*)d_in[10];
  const float* bo = (const float*)d_in[11];
  float* out = (float*)d_out;

  short* ws = (short*)d_ws;
  const size_t WSZ   = (size_t)DMODEL * DMODEL;
  const size_t QKVSZ = (size_t)BATCH * NHEAD * SEQ * DHEAD;
  short* Wt  = ws;                         // [4][1024][1024] bf16
  short* QKV = ws + 4 * WSZ;
  short* Qb  = QKV;
  short* Kb  = QKV + QKVSZ;
  short* Vb  = QKV + 2 * QKVSZ;
  short* Ctx = QKV + 3 * QKVSZ;
  // Mp overlays the Wq-transposed region (1 MB < 2 MB), written AFTER
  // proj_qkv has consumed Wt[0] (stream-serialized).
  unsigned long long* Mp = (unsigned long long*)ws;

  wtrans_kernel<<<dim3(16, 16, 4), 256, 0, stream>>>(Wq, Wk, Wv, Wo, Wt);
  proj_qkv_kernel<<<dim3(32, 8, 3), 256, 0, stream>>>(
      query_in, key_in, value_in, Wt, bq, bk, bv, QKV);
  mpack_kernel<<<dim3(1024), 256, 0, stream>>>(mask, Mp);
  attn_kernel<<<dim3(32, 32), 256, 0, stream>>>(Qb, Kb, Vb, Mp, Ctx);
  proj_out_kernel<<<dim3(32, 8), 256, 0, stream>>>(Ctx, Wt + 3 * WSZ, bo, out);
}